// Round 2
// baseline (214.695 us; speedup 1.0000x reference)
//
#include <hip/hip_runtime.h>
#include <hip/hip_bf16.h>
#include <math.h>

// HIR rainfall-runoff scan — tolerance-bracketed time-chunking + exact fixup.
//
// V3 changes vs V2 (120.8 us; pass1 ~52 us stall-bound at 1 wave/SIMD):
//  * pass1 lane-pairing: the lo/hi bracket chains run on ADJACENT LANES
//    (even lane: hi chain + gw; odd lane: lo chain) through one uniform
//    stepw() path — no divergence, initial state differs per lane. Merged
//    via __shfl_xor at warm-up end. Thread count doubles to 2*B*NC ->
//    2048 waves = 2 waves/SIMD, same total work: each wave's memory/issue
//    stalls hide under the other wave. (V2 measured 325 cy/step vs ~30 cy
//    dependent chain => stall-bound, needs TLP not fewer instructions.)
//  * pass2 -> dense work queue: pass1 atomically appends unmerged (b,c)
//    items; the fixup kernel grid-strides over the packed item list. Kills
//    the wave-max divergence of thread-per-(b,c) (P(wave has >=1 unmerged
//    lane) ~ 1, so V2's pass2 waves nearly all paid full recompute cost).
//
// Q[b,t] (t>=1) = fluxes from carry entering step t; Q[b,0] uses the FINAL
// carry (jnp.roll wraparound) with t=0 inputs (chunk NC-1 owner writes it).

struct P {
    float INSC, SMSC, RecK, g1, lc, k1, k2, k3, c2;
    // g1=1-RecK, lc=log2(COEFF), k1=SUB/SMSC, k2=CRAK/SMSC, k3=10/SMSC,
    // c2=-SQ/SMSC*log2(e)
};

__device__ __forceinline__ P make_params(const float* pINSC, const float* pCOEFF,
                                         const float* pSQ,   const float* pSMSC,
                                         const float* pSUB,  const float* pCRAK,
                                         const float* pRecK) {
    P p;
    p.INSC      = fminf(fmaxf(pINSC[0]  * 5.0f,   0.5f),   5.0f);
    float COEFF = fminf(fmaxf(pCOEFF[0] * 400.0f, 50.0f),  400.0f);
    float SQ    = fminf(fmaxf(pSQ[0]    * 6.0f,   0.0f),   6.0f);
    p.SMSC      = fminf(fmaxf(pSMSC[0]  * 500.0f, 50.0f),  500.0f);
    float SUB   = fminf(fmaxf(pSUB[0],  0.0f), 1.0f);
    float CRAK  = fminf(fmaxf(pCRAK[0], 0.0f), 1.0f);
    p.RecK      = fminf(fmaxf(pRecK[0]  * 0.3f,   0.003f), 0.3f);
    p.g1 = 1.0f - p.RecK;
    p.lc = log2f(COEFF);
    float inv = 1.0f / p.SMSC;
    p.k1 = SUB * inv;
    p.k2 = CRAK * inv;
    p.k3 = 10.0f * inv;
    p.c2 = (-SQ * inv) * 1.44269504088896340736f;
    return p;
}

// Full step with Q. Critical sms chain: fminf -> fmaf -> exp2f -> fminf ->
// mul -> fmaf. Everything else is off-path.
__device__ __forceinline__ float step(float Prec, float PET, float& sms, float& gw, const P& p) {
    float INT  = fminf(fminf(p.INSC, PET), Prec);
    float INR  = Prec - INT;
    float POT  = PET - INT;
    float S    = fminf(sms, p.SMSC);                 // lower clamp provably slack
    float u    = fmaf(-p.k1, S, 1.0f);
    float v    = fmaf(-p.k2, S, 1.0f);
    float ETS  = fminf(POT, p.k3 * S);
    float SmE  = S - ETS;
    float e    = exp2f(fmaf(p.c2, S, p.lc));         // cap = COEFF*2^(c2*S)
    float RMO  = fminf(INR, e);
    float w    = u * RMO;                            // t2 = RMO - SRUN
    float s2   = fmaf(v, w, SmE);                    // S + SMF - ETS
    float SMF  = v * w;
    float REC  = w - SMF;
    float RECnew = REC + fmaxf(s2 - p.SMSC, 0.0f);
    float BAS  = p.RecK * gw;
    float Q    = (INR - w) + BAS;                    // IRUN + SRUN + BAS
    gw  = fmaf(p.g1, gw, RECnew);
    sms = s2;
    return Q;
}

// Warm-up / state-advance step without Q (single chain, carries gw).
__device__ __forceinline__ void stepw(float Prec, float PET, float& sms, float& gw, const P& p) {
    float INT  = fminf(fminf(p.INSC, PET), Prec);
    float INR  = Prec - INT;
    float POT  = PET - INT;
    float S    = fminf(sms, p.SMSC);
    float u    = fmaf(-p.k1, S, 1.0f);
    float v    = fmaf(-p.k2, S, 1.0f);
    float ETS  = fminf(POT, p.k3 * S);
    float SmE  = S - ETS;
    float e    = exp2f(fmaf(p.c2, S, p.lc));
    float RMO  = fminf(INR, e);
    float w    = u * RMO;
    float s2   = fmaf(v, w, SmE);
    float SMF  = v * w;
    float REC  = w - SMF;
    float RECnew = REC + fmaxf(s2 - p.SMSC, 0.0f);
    gw  = fmaf(p.g1, gw, RECnew);
    sms = s2;
}

#define MERGE_TOL 0.75f

// Pass 1: 2*B*NC threads. Lane pair (2k, 2k+1) shares (b, c): even lane runs
// the hi bracket chain (+gw), odd lane the lo chain, through the SAME code
// path (initial s differs). Exchange via shfl_xor; even lane owns stores.
template<int T, int NC, int W>
__global__ __launch_bounds__(64, 1)
void hir_pass1(const float* __restrict__ inputs,
               const float* __restrict__ pINSC,  const float* __restrict__ pCOEFF,
               const float* __restrict__ pSQ,    const float* __restrict__ pSMSC,
               const float* __restrict__ pSUB,   const float* __restrict__ pCRAK,
               const float* __restrict__ pRecK,
               float* __restrict__ out, float4* __restrict__ st,
               unsigned int* __restrict__ qcount, unsigned int* __restrict__ qitems,
               int B)
{
    int gid = blockIdx.x * blockDim.x + threadIdx.x;
    int h  = gid & 1;            // 0 = hi chain (+gw, stores), 1 = lo chain
    int pb = gid >> 1;
    int b = pb % B;              // pair-consecutive rows
    int c = pb / B;              // wave-uniform (B % 32 == 0)
    if (c >= NC) return;

    P p = make_params(pINSC, pCOEFF, pSQ, pSMSC, pSUB, pCRAK, pRecK);

    const float4* __restrict__ rp = (const float4*)(inputs + (size_t)b * (2 * T));
    float* __restrict__ orow = out + (size_t)b * T;

    constexpr int CH = T / NC;             // 64 steps
    const int i1 = (c * CH) >> 1;          // first main float4 index
    int i0 = i1 - (W >> 1);                // warm-up start (W/2 float4s)
    const bool exact = (i0 <= 0);
    if (i0 < 0) i0 = 0;

    // exact chunks: both lanes run the true chain from 0 (identical values).
    float s  = exact ? 0.0f : (h ? 0.0f : p.SMSC);
    float gw = 0.0f;

    // ---- Warm-up: depth-2 pipeline of 4-float4 batches (8 steps each) ----
    const int nwb = (i1 - i0) >> 2;        // warm-up batches (count % 4 == 0)
    if (nwb > 0) {
        float4 A[4], Bq[4], C[4];
        #pragma unroll
        for (int j = 0; j < 4; ++j) A[j] = rp[i0 + j];
        {
            int k1b = (1 < nwb) ? 1 : 0;
            #pragma unroll
            for (int j = 0; j < 4; ++j) Bq[j] = rp[i0 + 4 * k1b + j];
        }
        for (int k = 0; k < nwb; ++k) {
            int kn = (k + 2 < nwb) ? (k + 2) : (nwb - 1);
            #pragma unroll
            for (int j = 0; j < 4; ++j) C[j] = rp[i0 + 4 * kn + j];
            #pragma unroll
            for (int j = 0; j < 4; ++j) {
                stepw(A[j].x, A[j].y, s, gw, p);
                stepw(A[j].z, A[j].w, s, gw, p);
            }
            #pragma unroll
            for (int j = 0; j < 4; ++j) { A[j] = Bq[j]; Bq[j] = C[j]; }
        }
    }

    // ---- Pair exchange: bracket merge + gw broadcast from even lane ----
    float so = __shfl_xor(s, 1);
    float go = __shfl_xor(gw, 1);
    float shi = h ? so : s;
    float slo = h ? s : so;
    gw = h ? go : gw;                      // correct gw lives on the even lane
    const bool merged = exact || ((shi - slo) <= MERGE_TOL);
    float sms = 0.5f * (slo + shi);        // == s for exact chunks

    // ---- Main chunk: 32 float4s, both lanes compute, even lane stores ----
    {
        constexpr int nmb = (CH / 2) / 4;  // 8 batches
        float4 A[4], Bq[4], C[4];
        #pragma unroll
        for (int j = 0; j < 4; ++j) A[j] = rp[i1 + j];
        #pragma unroll
        for (int j = 0; j < 4; ++j) Bq[j] = rp[i1 + 4 + j];
        for (int k = 0; k < nmb; ++k) {
            int kn = (k + 2 < nmb) ? (k + 2) : (nmb - 1);
            #pragma unroll
            for (int j = 0; j < 4; ++j) C[j] = rp[i1 + 4 * kn + j];
            int ibase = i1 + 4 * k;
            #pragma unroll
            for (int j = 0; j < 4; ++j) {
                float qa = step(A[j].x, A[j].y, sms, gw, p);
                float qb = step(A[j].z, A[j].w, sms, gw, p);
                if (!h) {
                    if (c == 0 && k == 0 && j == 0) {
                        orow[1] = qb;      // t=0 owned by the c=NC-1 path
                    } else {
                        ((float2*)orow)[ibase + j] = make_float2(qa, qb);
                    }
                }
            }
            #pragma unroll
            for (int j = 0; j < 4; ++j) { A[j] = Bq[j]; Bq[j] = C[j]; }
        }
    }

    if (!h) {
        st[(size_t)c * B + b] = make_float4(sms, gw, merged ? 1.0f : 0.0f, 0.0f);
        if (!merged) {
            unsigned int idx = atomicAdd(qcount, 1u);
            qitems[idx] = ((unsigned int)c << 24) | (unsigned int)b;
        }
        if (c == NC - 1) {
            float4 f0 = rp[0];
            float ss = sms, gg = gw;
            orow[0] = step(f0.x, f0.y, ss, gg, p);
        }
    }
}

// Parallel fixup over the DENSE unmerged-item queue. Each item (b,c) walks
// back to the nearest merged predecessor m (chunk 0 is always exact =>
// merged, so m exists), advances state store-free through chunks m+1..c-1
// (those chunks' own items rewrite their outputs), then recomputes chunk c
// with stores. Same semantics as the sequential per-row fixup: merged
// states are accepted as-is.
template<int T, int NC>
__global__ __launch_bounds__(64, 1)
void hir_fixup(const float* __restrict__ inputs,
               const float* __restrict__ pINSC,  const float* __restrict__ pCOEFF,
               const float* __restrict__ pSQ,    const float* __restrict__ pSMSC,
               const float* __restrict__ pSUB,   const float* __restrict__ pCRAK,
               const float* __restrict__ pRecK,
               float* __restrict__ out, const float4* __restrict__ st,
               const unsigned int* __restrict__ qcount,
               const unsigned int* __restrict__ qitems, int B)
{
    int gid = blockIdx.x * blockDim.x + threadIdx.x;
    int stride = gridDim.x * blockDim.x;
    int n = (int)*qcount;
    if (gid >= n) return;

    P p = make_params(pINSC, pCOEFF, pSQ, pSMSC, pSUB, pCRAK, pRecK);
    constexpr int CH = T / NC;

    for (int it = gid; it < n; it += stride) {
        unsigned int item = qitems[it];
        int b = (int)(item & 0xFFFFFFu);
        int c = (int)(item >> 24);

        const float4* __restrict__ rp = (const float4*)(inputs + (size_t)b * (2 * T));
        float* __restrict__ orow = out + (size_t)b * T;

        // Walk back to nearest merged predecessor (c >= 1: chunk 0 merged).
        int m = c - 1;
        float4 sm = st[(size_t)m * B + b];
        while (sm.z == 0.0f) { --m; sm = st[(size_t)m * B + b]; }
        float sms = sm.x, gw = sm.y;

        // Advance state through chunks m+1..c-1 (no stores).
        {
            const int ia = ((m + 1) * CH) >> 1;
            const int ib = (c * CH) >> 1;
            if (ia < ib) {
                float4 cur = rp[ia];
                for (int i = ia; i < ib; ++i) {
                    int ni = (i + 1 < ib) ? (i + 1) : i;
                    float4 nxt = rp[ni];
                    stepw(cur.x, cur.y, sms, gw, p);
                    stepw(cur.z, cur.w, sms, gw, p);
                    cur = nxt;
                }
            }
        }

        // Recompute chunk c exactly, with stores.
        {
            const int i1 = (c * CH) >> 1;
            const int i2 = ((c + 1) * CH) >> 1;
            float4 cur = rp[i1];
            for (int i = i1; i < i2; ++i) {
                int ni = (i + 1 < i2) ? (i + 1) : i;
                float4 nxt = rp[ni];
                float qa = step(cur.x, cur.y, sms, gw, p);
                float qb = step(cur.z, cur.w, sms, gw, p);
                ((float2*)orow)[i] = make_float2(qa, qb);
                cur = nxt;
            }
        }

        if (c == NC - 1) {                 // rewrite the t=0 wraparound output
            float4 f0 = rp[0];
            float ss = sms, gg = gw;
            orow[0] = step(f0.x, f0.y, ss, gg, p);
        }
    }
}

// Fallback: monolithic sequential (odd shapes / tiny workspace).
template<int T>
__global__ __launch_bounds__(64, 1)
void hir_scan_kernel(const float* __restrict__ inputs,
                     const float* __restrict__ pINSC,  const float* __restrict__ pCOEFF,
                     const float* __restrict__ pSQ,    const float* __restrict__ pSMSC,
                     const float* __restrict__ pSUB,   const float* __restrict__ pCRAK,
                     const float* __restrict__ pRecK,
                     float* __restrict__ out, int B)
{
    int b = blockIdx.x * blockDim.x + threadIdx.x;
    if (b >= B) return;
    P p = make_params(pINSC, pCOEFF, pSQ, pSMSC, pSUB, pCRAK, pRecK);
    const float4* __restrict__ rp = (const float4*)(inputs + (size_t)b * (2 * T));
    float* __restrict__ orow = out + (size_t)b * T;
    float sms = 0.0f, gw = 0.0f;
    float4 cur = rp[0];
    const float P0 = cur.x, E0 = cur.y;
    constexpr int NI = T / 2;
    for (int i = 0; i < NI; ++i) {
        int ni = (i + 1 < NI) ? (i + 1) : i;
        float4 nxt = rp[ni];
        float qa = step(cur.x, cur.y, sms, gw, p);
        float qb = step(cur.z, cur.w, sms, gw, p);
        if (i == 0) { orow[1] = qb; }
        else        { ((float2*)orow)[i] = make_float2(qa, qb); }
        cur = nxt;
    }
    float ss = sms, gg = gw;
    orow[0] = step(P0, E0, ss, gg, p);
}

extern "C" void kernel_launch(void* const* d_in, const int* in_sizes, int n_in,
                              void* d_out, int out_size, void* d_ws, size_t ws_size,
                              hipStream_t stream) {
    (void)n_in; (void)out_size;
    constexpr int T  = 1024;
    constexpr int NC = 16;    // chunks (CH=64)
    constexpr int W  = 320;   // warm-up steps: expected gap ~250*e^(-.0201*320)~0.4
    const float* inputs = (const float*)d_in[0];
    const float* INSC   = (const float*)d_in[1];
    const float* COEFF  = (const float*)d_in[2];
    const float* SQ     = (const float*)d_in[3];
    const float* SMSC   = (const float*)d_in[4];
    const float* SUB    = (const float*)d_in[5];
    const float* CRAK   = (const float*)d_in[6];
    const float* RecK   = (const float*)d_in[7];
    float* out = (float*)d_out;

    int B = in_sizes[0] / (2 * T);            // 4096 for the reference shape
    size_t stBytes = (size_t)B * NC * sizeof(float4);
    size_t need = stBytes + 64 + (size_t)B * NC * sizeof(unsigned int);

    if (ws_size < need || (B % 64) != 0) {
        int blocks = (B + 63) / 64;
        hir_scan_kernel<T><<<dim3(blocks), dim3(64), 0, stream>>>(
            inputs, INSC, COEFF, SQ, SMSC, SUB, CRAK, RecK, out, B);
        return;
    }

    float4* st = (float4*)d_ws;
    unsigned int* qcount = (unsigned int*)((char*)d_ws + stBytes);
    unsigned int* qitems = (unsigned int*)((char*)d_ws + stBytes + 64);

    hipMemsetAsync(qcount, 0, sizeof(unsigned int), stream);

    long total = 2L * B * NC;                 // 131072 threads = 2048 waves
    int blocks1 = (int)((total + 63) / 64);
    hir_pass1<T, NC, W><<<dim3(blocks1), dim3(64), 0, stream>>>(
        inputs, INSC, COEFF, SQ, SMSC, SUB, CRAK, RecK, out, st, qcount, qitems, B);

    int blocks2 = 1024;                        // 65536 threads >= worst-case items
    hir_fixup<T, NC><<<dim3(blocks2), dim3(64), 0, stream>>>(
        inputs, INSC, COEFF, SQ, SMSC, SUB, CRAK, RecK, out, st, qcount, qitems, B);
}

// Round 3
// 145.900 us; speedup vs baseline: 1.4715x; 1.4715x over previous
//
#include <hip/hip_runtime.h>
#include <hip/hip_bf16.h>
#include <math.h>

// HIR rainfall-runoff scan — tolerance-bracketed time-chunking + exact fixup.
//
// V4 changes vs V3 (214 us regression) / V2 (120.8 us best):
//  * V3 post-mortem: (a) single-address atomicAdd queue-append inside pass1
//    serialized thousands of RMWs on one cacheline (~+90 us tail, VALUBusy
//    22%); (b) lane-pairing duplicated main-chunk work. Both reverted.
//  * Real pass1 bottleneck (V2: 325 cy/step vs ~30 cy dep chain, VALUBusy
//    35%): lane i reads row base+i at 8 KB stride => every vector load
//    scatters to 64 distinct cache lines (VMEM-transaction-bound).
//  * Fix: time-major staging. Within a pass1 wave, time is lockstep and b is
//    lane-consecutive => transpose inputs to tp[t][b] (512 B contiguous wave
//    loads, 8x fewer transactions, L2/L3-resident) and write Q to qtp[t][b]
//    (256 B contiguous wave stores), transpose back at the end.
//  * Fixup queue kept, but built contention-free in a separate kernel via
//    wave ballot-compaction: ONE atomicAdd per wave (<=1024 total). Fixup
//    grid-strides the dense item list, reads the original [b][t] layout
//    (per-thread sequential), writes qtp.
//  * Falls back to the V2 two-kernel path if workspace < ~50 MB.
//
// Q[b,t] (t>=1) = fluxes from carry entering step t; Q[b,0] uses the FINAL
// carry (jnp.roll wraparound) with t=0 inputs (chunk NC-1 owner writes it).

struct P {
    float INSC, SMSC, RecK, g1, lc, k1, k2, k3, c2;
    // g1=1-RecK, lc=log2(COEFF), k1=SUB/SMSC, k2=CRAK/SMSC, k3=10/SMSC,
    // c2=-SQ/SMSC*log2(e)
};

__device__ __forceinline__ P make_params(const float* pINSC, const float* pCOEFF,
                                         const float* pSQ,   const float* pSMSC,
                                         const float* pSUB,  const float* pCRAK,
                                         const float* pRecK) {
    P p;
    p.INSC      = fminf(fmaxf(pINSC[0]  * 5.0f,   0.5f),   5.0f);
    float COEFF = fminf(fmaxf(pCOEFF[0] * 400.0f, 50.0f),  400.0f);
    float SQ    = fminf(fmaxf(pSQ[0]    * 6.0f,   0.0f),   6.0f);
    p.SMSC      = fminf(fmaxf(pSMSC[0]  * 500.0f, 50.0f),  500.0f);
    float SUB   = fminf(fmaxf(pSUB[0],  0.0f), 1.0f);
    float CRAK  = fminf(fmaxf(pCRAK[0], 0.0f), 1.0f);
    p.RecK      = fminf(fmaxf(pRecK[0]  * 0.3f,   0.003f), 0.3f);
    p.g1 = 1.0f - p.RecK;
    p.lc = log2f(COEFF);
    float inv = 1.0f / p.SMSC;
    p.k1 = SUB * inv;
    p.k2 = CRAK * inv;
    p.k3 = 10.0f * inv;
    p.c2 = (-SQ * inv) * 1.44269504088896340736f;
    return p;
}

// Full step with Q. Critical sms chain: fminf -> fmaf -> exp2f -> fminf ->
// mul -> fmaf. Everything else is off-path.
__device__ __forceinline__ float step(float Prec, float PET, float& sms, float& gw, const P& p) {
    float INT  = fminf(fminf(p.INSC, PET), Prec);
    float INR  = Prec - INT;
    float POT  = PET - INT;
    float S    = fminf(sms, p.SMSC);                 // lower clamp provably slack
    float u    = fmaf(-p.k1, S, 1.0f);
    float v    = fmaf(-p.k2, S, 1.0f);
    float ETS  = fminf(POT, p.k3 * S);
    float SmE  = S - ETS;
    float e    = exp2f(fmaf(p.c2, S, p.lc));         // cap = COEFF*2^(c2*S)
    float RMO  = fminf(INR, e);
    float w    = u * RMO;                            // t2 = RMO - SRUN
    float s2   = fmaf(v, w, SmE);                    // S + SMF - ETS
    float SMF  = v * w;
    float REC  = w - SMF;
    float RECnew = REC + fmaxf(s2 - p.SMSC, 0.0f);
    float BAS  = p.RecK * gw;
    float Q    = (INR - w) + BAS;                    // IRUN + SRUN + BAS
    gw  = fmaf(p.g1, gw, RECnew);
    sms = s2;
    return Q;
}

// Warm-up / state-advance step without Q (single chain, carries gw).
__device__ __forceinline__ void stepw(float Prec, float PET, float& sms, float& gw, const P& p) {
    float INT  = fminf(fminf(p.INSC, PET), Prec);
    float INR  = Prec - INT;
    float POT  = PET - INT;
    float S    = fminf(sms, p.SMSC);
    float u    = fmaf(-p.k1, S, 1.0f);
    float v    = fmaf(-p.k2, S, 1.0f);
    float ETS  = fminf(POT, p.k3 * S);
    float SmE  = S - ETS;
    float e    = exp2f(fmaf(p.c2, S, p.lc));
    float RMO  = fminf(INR, e);
    float w    = u * RMO;
    float s2   = fmaf(v, w, SmE);
    float SMF  = v * w;
    float REC  = w - SMF;
    float RECnew = REC + fmaxf(s2 - p.SMSC, 0.0f);
    gw  = fmaf(p.g1, gw, RECnew);
    sms = s2;
}

// Dual-bracket warm-up step: hi chain carries gw; lo chain is sms-only.
__device__ __forceinline__ void dstep(float Prec, float PET,
                                      float& slo, float& shi, float& gw, const P& p) {
    float INT = fminf(fminf(p.INSC, PET), Prec);
    float INR = Prec - INT;
    float POT = PET - INT;
    {   // hi + gw
        float S    = fminf(shi, p.SMSC);
        float u    = fmaf(-p.k1, S, 1.0f);
        float v    = fmaf(-p.k2, S, 1.0f);
        float ETS  = fminf(POT, p.k3 * S);
        float SmE  = S - ETS;
        float e    = exp2f(fmaf(p.c2, S, p.lc));
        float RMO  = fminf(INR, e);
        float w    = u * RMO;
        float s2   = fmaf(v, w, SmE);
        float SMF  = v * w;
        float REC  = w - SMF;
        float RECnew = REC + fmaxf(s2 - p.SMSC, 0.0f);
        gw  = fmaf(p.g1, gw, RECnew);
        shi = s2;
    }
    {   // lo, sms only
        float S    = fminf(slo, p.SMSC);
        float u    = fmaf(-p.k1, S, 1.0f);
        float v    = fmaf(-p.k2, S, 1.0f);
        float ETS  = fminf(POT, p.k3 * S);
        float SmE  = S - ETS;
        float e    = exp2f(fmaf(p.c2, S, p.lc));
        float RMO  = fminf(INR, e);
        float w    = u * RMO;
        slo = fmaf(v, w, SmE);
    }
}

#define MERGE_TOL 0.75f

// ---------------------------------------------------------------------------
// Transposes: inputs[b][t] (float2 Prec,PET) -> tp[t][b];  qtp[t][b] -> out[b][t]
// ---------------------------------------------------------------------------

__global__ __launch_bounds__(256)
void transpose_in(const float2* __restrict__ in, float2* __restrict__ tp,
                  int B, int Tdim)
{
    __shared__ float2 tile[64][65];
    int t0 = blockIdx.x * 64, b0 = blockIdx.y * 64;
    int l = threadIdx.x & 63, w = threadIdx.x >> 6;
    #pragma unroll
    for (int j = 0; j < 16; ++j) {
        int bb = w * 16 + j;
        tile[l][bb] = in[(long)(b0 + bb) * Tdim + t0 + l];   // coalesced along t
    }
    __syncthreads();
    #pragma unroll
    for (int j = 0; j < 16; ++j) {
        int tt = w * 16 + j;
        tp[(long)(t0 + tt) * B + b0 + l] = tile[tt][l];      // coalesced along b
    }
}

__global__ __launch_bounds__(256)
void transpose_out(const float* __restrict__ qtp, float* __restrict__ out,
                   int B, int Tdim)
{
    __shared__ float tile[64][65];
    int t0 = blockIdx.x * 64, b0 = blockIdx.y * 64;
    int l = threadIdx.x & 63, w = threadIdx.x >> 6;
    #pragma unroll
    for (int j = 0; j < 16; ++j) {
        int tt = w * 16 + j;
        tile[tt][l] = qtp[(long)(t0 + tt) * B + b0 + l];     // coalesced along b
    }
    __syncthreads();
    #pragma unroll
    for (int j = 0; j < 16; ++j) {
        int bb = w * 16 + j;
        out[(long)(b0 + bb) * Tdim + t0 + l] = tile[l][bb];  // coalesced along t
    }
}

// ---------------------------------------------------------------------------
// Pass 1 (time-major): one thread per (b, c); b lane-consecutive, c uniform.
// All loads tp[t*B+b] are 512 B contiguous per wave; Q stores to qtp[t*B+b]
// are 256 B contiguous. No atomics.
// ---------------------------------------------------------------------------

template<int T, int NC, int W>
__global__ __launch_bounds__(64, 1)
void hir_pass1t(const float2* __restrict__ tp,
                const float* __restrict__ pINSC,  const float* __restrict__ pCOEFF,
                const float* __restrict__ pSQ,    const float* __restrict__ pSMSC,
                const float* __restrict__ pSUB,   const float* __restrict__ pCRAK,
                const float* __restrict__ pRecK,
                float* __restrict__ qtp, float4* __restrict__ st, int B)
{
    int gid = blockIdx.x * blockDim.x + threadIdx.x;
    int b = gid % B;            // consecutive lanes -> consecutive columns
    int c = gid / B;            // wave-uniform (B % 64 == 0)
    if (c >= NC) return;

    P p = make_params(pINSC, pCOEFF, pSQ, pSMSC, pSUB, pCRAK, pRecK);

    const float2* __restrict__ col = tp + b;   // element t at col[(long)t*B]

    constexpr int CH = T / NC;             // 64 steps
    const int t1 = c * CH;
    int t0 = t1 - W;
    const bool exact = (t0 <= 0);
    if (t0 < 0) t0 = 0;

    float slo = 0.0f, shi = exact ? 0.0f : p.SMSC, gw = 0.0f;

    // ---- Warm-up: depth-2 pipeline of 8-step batches ----
    const int nwb = (t1 - t0) >> 3;        // (t1-t0) is a multiple of 8
    if (nwb > 0) {
        float2 A[8], Bq[8], C[8];
        #pragma unroll
        for (int j = 0; j < 8; ++j) A[j] = col[(long)(t0 + j) * B];
        {
            int tB = t0 + ((1 < nwb) ? 8 : 0);
            #pragma unroll
            for (int j = 0; j < 8; ++j) Bq[j] = col[(long)(tB + j) * B];
        }
        if (exact) {
            for (int k = 0; k < nwb; ++k) {
                int kn = (k + 2 < nwb) ? (k + 2) : (nwb - 1);
                #pragma unroll
                for (int j = 0; j < 8; ++j) C[j] = col[(long)(t0 + 8 * kn + j) * B];
                #pragma unroll
                for (int j = 0; j < 8; ++j) stepw(A[j].x, A[j].y, shi, gw, p);
                #pragma unroll
                for (int j = 0; j < 8; ++j) { A[j] = Bq[j]; Bq[j] = C[j]; }
            }
            slo = shi;
        } else {
            for (int k = 0; k < nwb; ++k) {
                int kn = (k + 2 < nwb) ? (k + 2) : (nwb - 1);
                #pragma unroll
                for (int j = 0; j < 8; ++j) C[j] = col[(long)(t0 + 8 * kn + j) * B];
                #pragma unroll
                for (int j = 0; j < 8; ++j) dstep(A[j].x, A[j].y, slo, shi, gw, p);
                #pragma unroll
                for (int j = 0; j < 8; ++j) { A[j] = Bq[j]; Bq[j] = C[j]; }
            }
        }
    }
    const bool merged = exact || ((shi - slo) <= MERGE_TOL);
    float sms = exact ? shi : (0.5f * (slo + shi));

    // ---- Main chunk: 64 steps, depth-2 pipeline, coalesced Q stores ----
    {
        constexpr int nmb = CH / 8;        // 8 batches
        float2 A[8], Bq[8], C[8];
        #pragma unroll
        for (int j = 0; j < 8; ++j) A[j] = col[(long)(t1 + j) * B];
        #pragma unroll
        for (int j = 0; j < 8; ++j) Bq[j] = col[(long)(t1 + 8 + j) * B];
        for (int k = 0; k < nmb; ++k) {
            int kn = (k + 2 < nmb) ? (k + 2) : (nmb - 1);
            #pragma unroll
            for (int j = 0; j < 8; ++j) C[j] = col[(long)(t1 + 8 * kn + j) * B];
            int tb = t1 + 8 * k;
            #pragma unroll
            for (int j = 0; j < 8; ++j) {
                float q = step(A[j].x, A[j].y, sms, gw, p);
                int t = tb + j;
                if (!(c == 0 && t == 0)) {         // wave-uniform condition
                    qtp[(long)t * B + b] = q;      // t=0 owned by wraparound
                }
            }
            #pragma unroll
            for (int j = 0; j < 8; ++j) { A[j] = Bq[j]; Bq[j] = C[j]; }
        }
    }

    st[(size_t)c * B + b] = make_float4(sms, gw, merged ? 1.0f : 0.0f, 0.0f);

    if (c == NC - 1) {                     // Q[b,0] from final carry (roll)
        float2 f0 = col[0];
        float ss = sms, gg = gw;
        qtp[b] = step(f0.x, f0.y, ss, gg, p);
    }
}

// ---------------------------------------------------------------------------
// Queue build: wave ballot-compaction, ONE atomicAdd per wave (<=1024 total).
// Item encoding: gid = c*B + b (st's linear index).
// ---------------------------------------------------------------------------

__global__ __launch_bounds__(64)
void build_queue(const float4* __restrict__ st, unsigned int* __restrict__ qcount,
                 unsigned int* __restrict__ qitems, int n)
{
    int gid = blockIdx.x * blockDim.x + threadIdx.x;
    bool un = false;
    if (gid < n) un = (st[gid].z == 0.0f);
    unsigned long long mask = __ballot(un);
    int lane = threadIdx.x;                // blockDim == 64 == one wave
    int cnt = __popcll(mask);
    unsigned int base = 0;
    if (lane == 0 && cnt) base = atomicAdd(qcount, (unsigned int)cnt);
    base = (unsigned int)__shfl((int)base, 0);
    if (un) {
        int pre = __popcll(mask & ((1ull << lane) - 1ull));
        qitems[base + pre] = (unsigned int)gid;
    }
}

// ---------------------------------------------------------------------------
// Fixup over the dense unmerged-item queue. Reads the ORIGINAL [b][t] inputs
// (per-thread sequential float4s), writes qtp. Each item (b,c) walks back to
// the nearest merged predecessor m (chunk 0 always exact => merged), advances
// state store-free through m+1..c-1, then recomputes chunk c with stores.
// Same semantics as the sequential per-row fixup.
// ---------------------------------------------------------------------------

template<int T, int NC>
__global__ __launch_bounds__(64)
void hir_fixup(const float* __restrict__ inputs,
               const float* __restrict__ pINSC,  const float* __restrict__ pCOEFF,
               const float* __restrict__ pSQ,    const float* __restrict__ pSMSC,
               const float* __restrict__ pSUB,   const float* __restrict__ pCRAK,
               const float* __restrict__ pRecK,
               float* __restrict__ qtp, const float4* __restrict__ st,
               const unsigned int* __restrict__ qcount,
               const unsigned int* __restrict__ qitems, int B)
{
    int gid = blockIdx.x * blockDim.x + threadIdx.x;
    int stride = gridDim.x * blockDim.x;
    int n = (int)*qcount;

    P p = make_params(pINSC, pCOEFF, pSQ, pSMSC, pSUB, pCRAK, pRecK);
    constexpr int CH = T / NC;

    for (int it = gid; it < n; it += stride) {
        unsigned int item = qitems[it];
        int b = (int)(item % (unsigned int)B);
        int c = (int)(item / (unsigned int)B);

        const float4* __restrict__ rp = (const float4*)(inputs + (size_t)b * (2 * T));

        // Walk back to nearest merged predecessor (c >= 1: chunk 0 merged).
        int m = c - 1;
        float4 sm = st[(size_t)m * B + b];
        while (sm.z == 0.0f) { --m; sm = st[(size_t)m * B + b]; }
        float sms = sm.x, gw = sm.y;

        // Advance state through chunks m+1..c-1 (no stores).
        {
            const int ia = ((m + 1) * CH) >> 1;
            const int ib = (c * CH) >> 1;
            if (ia < ib) {
                float4 cur = rp[ia];
                for (int i = ia; i < ib; ++i) {
                    int ni = (i + 1 < ib) ? (i + 1) : i;
                    float4 nxt = rp[ni];
                    stepw(cur.x, cur.y, sms, gw, p);
                    stepw(cur.z, cur.w, sms, gw, p);
                    cur = nxt;
                }
            }
        }

        // Recompute chunk c exactly, with stores into qtp[t][b].
        {
            const int i1 = (c * CH) >> 1;
            const int i2 = ((c + 1) * CH) >> 1;
            float4 cur = rp[i1];
            for (int i = i1; i < i2; ++i) {
                int ni = (i + 1 < i2) ? (i + 1) : i;
                float4 nxt = rp[ni];
                float qa = step(cur.x, cur.y, sms, gw, p);
                float qb = step(cur.z, cur.w, sms, gw, p);
                qtp[(long)(2 * i) * B + b]     = qa;
                qtp[(long)(2 * i + 1) * B + b] = qb;
                cur = nxt;
            }
        }

        if (c == NC - 1) {                 // rewrite the t=0 wraparound output
            float4 f0 = rp[0];
            float ss = sms, gg = gw;
            qtp[b] = step(f0.x, f0.y, ss, gg, p);
        }
    }
}

// ---------------------------------------------------------------------------
// Legacy V2 path (fallback when workspace < ~50 MB): scattered-load pass1 +
// sequential per-row pass2. Known-good at 120.8 us.
// ---------------------------------------------------------------------------

template<int T, int NC, int W>
__global__ __launch_bounds__(64, 1)
void hir_pass1_legacy(const float* __restrict__ inputs,
               const float* __restrict__ pINSC,  const float* __restrict__ pCOEFF,
               const float* __restrict__ pSQ,    const float* __restrict__ pSMSC,
               const float* __restrict__ pSUB,   const float* __restrict__ pCRAK,
               const float* __restrict__ pRecK,
               float* __restrict__ out, float4* __restrict__ st, int B)
{
    int gid = blockIdx.x * blockDim.x + threadIdx.x;
    int b = gid % B;
    int c = gid / B;
    if (c >= NC) return;

    P p = make_params(pINSC, pCOEFF, pSQ, pSMSC, pSUB, pCRAK, pRecK);

    const float4* __restrict__ rp = (const float4*)(inputs + (size_t)b * (2 * T));
    float* __restrict__ orow = out + (size_t)b * T;

    constexpr int CH = T / NC;
    const int i1 = (c * CH) >> 1;
    int i0 = i1 - (W >> 1);
    const bool exact = (i0 <= 0);
    if (i0 < 0) i0 = 0;

    float slo = 0.0f, shi = exact ? 0.0f : p.SMSC, gw = 0.0f;

    const int nwb = (i1 - i0) >> 2;
    if (nwb > 0) {
        float4 A[4], Bq[4], C[4];
        #pragma unroll
        for (int j = 0; j < 4; ++j) A[j] = rp[i0 + j];
        {
            int k1b = (1 < nwb) ? 1 : 0;
            #pragma unroll
            for (int j = 0; j < 4; ++j) Bq[j] = rp[i0 + 4 * k1b + j];
        }
        if (exact) {
            for (int k = 0; k < nwb; ++k) {
                int kn = (k + 2 < nwb) ? (k + 2) : (nwb - 1);
                #pragma unroll
                for (int j = 0; j < 4; ++j) C[j] = rp[i0 + 4 * kn + j];
                #pragma unroll
                for (int j = 0; j < 4; ++j) {
                    stepw(A[j].x, A[j].y, shi, gw, p);
                    stepw(A[j].z, A[j].w, shi, gw, p);
                }
                #pragma unroll
                for (int j = 0; j < 4; ++j) { A[j] = Bq[j]; Bq[j] = C[j]; }
            }
            slo = shi;
        } else {
            for (int k = 0; k < nwb; ++k) {
                int kn = (k + 2 < nwb) ? (k + 2) : (nwb - 1);
                #pragma unroll
                for (int j = 0; j < 4; ++j) C[j] = rp[i0 + 4 * kn + j];
                #pragma unroll
                for (int j = 0; j < 4; ++j) {
                    dstep(A[j].x, A[j].y, slo, shi, gw, p);
                    dstep(A[j].z, A[j].w, slo, shi, gw, p);
                }
                #pragma unroll
                for (int j = 0; j < 4; ++j) { A[j] = Bq[j]; Bq[j] = C[j]; }
            }
        }
    }
    const bool merged = exact || ((shi - slo) <= MERGE_TOL);
    float sms = exact ? shi : (0.5f * (slo + shi));

    {
        constexpr int nmb = (CH / 2) / 4;
        float4 A[4], Bq[4], C[4];
        #pragma unroll
        for (int j = 0; j < 4; ++j) A[j] = rp[i1 + j];
        #pragma unroll
        for (int j = 0; j < 4; ++j) Bq[j] = rp[i1 + 4 + j];
        for (int k = 0; k < nmb; ++k) {
            int kn = (k + 2 < nmb) ? (k + 2) : (nmb - 1);
            #pragma unroll
            for (int j = 0; j < 4; ++j) C[j] = rp[i1 + 4 * kn + j];
            int ibase = i1 + 4 * k;
            #pragma unroll
            for (int j = 0; j < 4; ++j) {
                float qa = step(A[j].x, A[j].y, sms, gw, p);
                float qb = step(A[j].z, A[j].w, sms, gw, p);
                if (c == 0 && k == 0 && j == 0) {
                    orow[1] = qb;
                } else {
                    ((float2*)orow)[ibase + j] = make_float2(qa, qb);
                }
            }
            #pragma unroll
            for (int j = 0; j < 4; ++j) { A[j] = Bq[j]; Bq[j] = C[j]; }
        }
    }

    st[(size_t)c * B + b] = make_float4(sms, gw, merged ? 1.0f : 0.0f, 0.0f);

    if (c == NC - 1) {
        float4 f0 = rp[0];
        float ss = sms, gg = gw;
        orow[0] = step(f0.x, f0.y, ss, gg, p);
    }
}

template<int T, int NC>
__global__ __launch_bounds__(64, 1)
void hir_pass2_legacy(const float* __restrict__ inputs,
               const float* __restrict__ pINSC,  const float* __restrict__ pCOEFF,
               const float* __restrict__ pSQ,    const float* __restrict__ pSMSC,
               const float* __restrict__ pSUB,   const float* __restrict__ pCRAK,
               const float* __restrict__ pRecK,
               float* __restrict__ out, const float4* __restrict__ st, int B)
{
    int b = blockIdx.x * blockDim.x + threadIdx.x;
    if (b >= B) return;

    P p = make_params(pINSC, pCOEFF, pSQ, pSMSC, pSUB, pCRAK, pRecK);
    constexpr int CH = T / NC;

    const float4* __restrict__ rp = (const float4*)(inputs + (size_t)b * (2 * T));
    float* __restrict__ orow = out + (size_t)b * T;

    float4 s0 = st[b];
    float ex_s = s0.x, ex_g = s0.y;

    for (int c = 1; c < NC; ++c) {
        float4 sc = st[(size_t)c * B + b];
        if (sc.z != 0.0f) {
            ex_s = sc.x; ex_g = sc.y;
            continue;
        }
        float sms = ex_s, gw = ex_g;
        const int i1 = (c * CH) >> 1;
        const int i2 = ((c + 1) * CH) >> 1;
        float4 cur = rp[i1];
        for (int i = i1; i < i2; ++i) {
            int ni = (i + 1 < i2) ? (i + 1) : i;
            float4 nxt = rp[ni];
            float qa = step(cur.x, cur.y, sms, gw, p);
            float qb = step(cur.z, cur.w, sms, gw, p);
            ((float2*)orow)[i] = make_float2(qa, qb);
            cur = nxt;
        }
        ex_s = sms; ex_g = gw;
        if (c == NC - 1) {
            float4 f0 = rp[0];
            float ss = sms, gg = gw;
            orow[0] = step(f0.x, f0.y, ss, gg, p);
        }
    }
}

// Fallback: monolithic sequential (odd shapes / tiny workspace).
template<int T>
__global__ __launch_bounds__(64, 1)
void hir_scan_kernel(const float* __restrict__ inputs,
                     const float* __restrict__ pINSC,  const float* __restrict__ pCOEFF,
                     const float* __restrict__ pSQ,    const float* __restrict__ pSMSC,
                     const float* __restrict__ pSUB,   const float* __restrict__ pCRAK,
                     const float* __restrict__ pRecK,
                     float* __restrict__ out, int B)
{
    int b = blockIdx.x * blockDim.x + threadIdx.x;
    if (b >= B) return;
    P p = make_params(pINSC, pCOEFF, pSQ, pSMSC, pSUB, pCRAK, pRecK);
    const float4* __restrict__ rp = (const float4*)(inputs + (size_t)b * (2 * T));
    float* __restrict__ orow = out + (size_t)b * T;
    float sms = 0.0f, gw = 0.0f;
    float4 cur = rp[0];
    const float P0 = cur.x, E0 = cur.y;
    constexpr int NI = T / 2;
    for (int i = 0; i < NI; ++i) {
        int ni = (i + 1 < NI) ? (i + 1) : i;
        float4 nxt = rp[ni];
        float qa = step(cur.x, cur.y, sms, gw, p);
        float qb = step(cur.z, cur.w, sms, gw, p);
        if (i == 0) { orow[1] = qb; }
        else        { ((float2*)orow)[i] = make_float2(qa, qb); }
        cur = nxt;
    }
    float ss = sms, gg = gw;
    orow[0] = step(P0, E0, ss, gg, p);
}

extern "C" void kernel_launch(void* const* d_in, const int* in_sizes, int n_in,
                              void* d_out, int out_size, void* d_ws, size_t ws_size,
                              hipStream_t stream) {
    (void)n_in; (void)out_size;
    constexpr int T  = 1024;
    constexpr int NC = 16;    // chunks (CH=64)
    constexpr int W  = 320;   // warm-up steps: expected gap ~250*e^(-.0201*320)~0.4
    const float* inputs = (const float*)d_in[0];
    const float* INSC   = (const float*)d_in[1];
    const float* COEFF  = (const float*)d_in[2];
    const float* SQ     = (const float*)d_in[3];
    const float* SMSC   = (const float*)d_in[4];
    const float* SUB    = (const float*)d_in[5];
    const float* CRAK   = (const float*)d_in[6];
    const float* RecK   = (const float*)d_in[7];
    float* out = (float*)d_out;

    int B = in_sizes[0] / (2 * T);            // 4096 for the reference shape
    size_t tpBytes  = (size_t)B * T * sizeof(float2);   // 32 MB
    size_t qtpBytes = (size_t)B * T * sizeof(float);    // 16 MB
    size_t stBytes  = (size_t)B * NC * sizeof(float4);  //  1 MB
    size_t qBytes   = (size_t)B * NC * sizeof(unsigned int);
    size_t bigNeed  = tpBytes + qtpBytes + stBytes + 64 + qBytes;

    if ((B % 64) == 0 && ws_size >= bigNeed) {
        // ---- Time-major pipeline ----
        float2* tp = (float2*)d_ws;
        float*  qtp = (float*)((char*)d_ws + tpBytes);
        float4* st  = (float4*)((char*)d_ws + tpBytes + qtpBytes);
        unsigned int* qcount = (unsigned int*)((char*)d_ws + tpBytes + qtpBytes + stBytes);
        unsigned int* qitems = (unsigned int*)((char*)d_ws + tpBytes + qtpBytes + stBytes + 64);

        hipMemsetAsync(qcount, 0, sizeof(unsigned int), stream);

        transpose_in<<<dim3(T / 64, B / 64), dim3(256), 0, stream>>>(
            (const float2*)inputs, tp, B, T);

        long total = (long)B * NC;            // 65536 threads = 1024 waves
        int blocks1 = (int)((total + 63) / 64);
        hir_pass1t<T, NC, W><<<dim3(blocks1), dim3(64), 0, stream>>>(
            tp, INSC, COEFF, SQ, SMSC, SUB, CRAK, RecK, qtp, st, B);

        build_queue<<<dim3(blocks1), dim3(64), 0, stream>>>(
            st, qcount, qitems, (int)total);

        hir_fixup<T, NC><<<dim3(1024), dim3(64), 0, stream>>>(
            inputs, INSC, COEFF, SQ, SMSC, SUB, CRAK, RecK, qtp, st, qcount, qitems, B);

        transpose_out<<<dim3(T / 64, B / 64), dim3(256), 0, stream>>>(
            qtp, out, B, T);
        return;
    }

    if ((B % 64) == 0 && ws_size >= stBytes) {
        // ---- Legacy V2 path ----
        float4* st = (float4*)d_ws;
        long total = (long)B * NC;
        int blocks1 = (int)((total + 63) / 64);
        hir_pass1_legacy<T, NC, W><<<dim3(blocks1), dim3(64), 0, stream>>>(
            inputs, INSC, COEFF, SQ, SMSC, SUB, CRAK, RecK, out, st, B);
        int blocks2 = (B + 63) / 64;
        hir_pass2_legacy<T, NC><<<dim3(blocks2), dim3(64), 0, stream>>>(
            inputs, INSC, COEFF, SQ, SMSC, SUB, CRAK, RecK, out, st, B);
        return;
    }

    int blocks = (B + 63) / 64;
    hir_scan_kernel<T><<<dim3(blocks), dim3(64), 0, stream>>>(
        inputs, INSC, COEFF, SQ, SMSC, SUB, CRAK, RecK, out, B);
}